// Round 1
// baseline (150.579 us; speedup 1.0000x reference)
//
#include <hip/hip_runtime.h>
#include <cmath>

#define THREADS 256
#define QC 24000
#define NCLS 80
#define NTOP 300
#define NHIST 4096
#define CAND_CAP 2048

// monotonic unsigned key for fp32 (total order matching float compare)
__device__ __forceinline__ unsigned fkey(float x) {
    unsigned b = __float_as_uint(x);
    return (b & 0x80000000u) ? ~b : (b | 0x80000000u);
}

// Replicate float32 sigmoid: 1/(1+expf(-x)) with correctly-rounded expf.
// double exp then round to f32 == CR expf except ~2^-29 double-rounding cases.
__device__ __forceinline__ float sigmoid_ref(float x) {
    float ef = (float)exp(-(double)x);
    return 1.0f / (1.0f + ef);
}

__global__ __launch_bounds__(THREADS, 4) void postproc_kernel(
    const float* __restrict__ logits,   // [B, 300, 80]
    const float* __restrict__ pboxes,   // [B, 300, 4]
    const float* __restrict__ osizes,   // [B, 2]
    float* __restrict__ out_boxes,      // [B, 300, 4]
    float* __restrict__ out_labels,     // [B, 300] (as float)
    float* __restrict__ out_scores)     // [B, 300]
{
    const int b = blockIdx.x;
    const int tid = threadIdx.x;
    const float* __restrict__ row = logits + (size_t)b * QC;
    const float4* __restrict__ row4 = (const float4*)row;

    __shared__ unsigned hist[NHIST];
    __shared__ unsigned long long cand[CAND_CAP];
    __shared__ unsigned psum[THREADS];
    __shared__ int s_ncand;
    __shared__ unsigned s_thresh;

    for (int i = tid; i < NHIST; i += THREADS) hist[i] = 0u;
    if (tid == 0) s_ncand = 0;
    __syncthreads();

    // ---- pass 1: histogram of top-12 key bits ----
    for (int i = tid; i < QC / 4; i += THREADS) {
        float4 v = row4[i];
        atomicAdd(&hist[fkey(v.x) >> 20], 1u);
        atomicAdd(&hist[fkey(v.y) >> 20], 1u);
        atomicAdd(&hist[fkey(v.z) >> 20], 1u);
        atomicAdd(&hist[fkey(v.w) >> 20], 1u);
    }
    __syncthreads();

    // ---- suffix scan (descending buckets) to find threshold bucket ----
    const int base = NHIST - 1 - tid * 16;   // this thread's chunk: base .. base-15
    unsigned partial = 0;
    #pragma unroll
    for (int s = 0; s < 16; ++s) partial += hist[base - s];
    psum[tid] = partial;
    __syncthreads();
    for (int off = 1; off < THREADS; off <<= 1) {
        unsigned v = (tid >= off) ? psum[tid - off] : 0u;
        __syncthreads();
        psum[tid] += v;
        __syncthreads();
    }
    unsigned incl = psum[tid];
    unsigned excl = incl - partial;
    if (excl < NTOP && incl >= NTOP) {      // crossing is inside my chunk (unique thread)
        unsigned cum = excl;
        #pragma unroll
        for (int s = 0; s < 16; ++s) {
            cum += hist[base - s];
            if (cum >= NTOP) { s_thresh = (unsigned)(base - s) << 20; break; }
        }
    }
    __syncthreads();
    const unsigned thresh = s_thresh;

    // ---- pass 2: collect candidates (score_bits << 32 | ~idx) ----
    for (int i = tid; i < QC / 4; i += THREADS) {
        float4 v = row4[i];
        float vals[4] = {v.x, v.y, v.z, v.w};
        #pragma unroll
        for (int s = 0; s < 4; ++s) {
            if (fkey(vals[s]) >= thresh) {
                int pos = atomicAdd(&s_ncand, 1);
                if (pos < CAND_CAP) {
                    unsigned idx = (unsigned)(i * 4 + s);
                    float sc = sigmoid_ref(vals[s]);
                    cand[pos] = ((unsigned long long)__float_as_uint(sc) << 32)
                              | (unsigned long long)(~idx);
                }
            }
        }
    }
    __syncthreads();
    const int ncand = min(s_ncand, CAND_CAP);
    int npad = 512;
    while (npad < ncand) npad <<= 1;
    for (int i = ncand + tid; i < npad; i += THREADS) cand[i] = 0ull;
    __syncthreads();

    // ---- bitonic sort, descending on composite key ----
    for (int k = 2; k <= npad; k <<= 1) {
        for (int j = k >> 1; j > 0; j >>= 1) {
            for (int t = tid; t < (npad >> 1); t += THREADS) {
                int i = ((t & ~(j - 1)) << 1) | (t & (j - 1));
                int ixj = i | j;
                unsigned long long a = cand[i], c = cand[ixj];
                bool desc = (i & k) == 0;
                bool sw = desc ? (a < c) : (a > c);
                if (sw) { cand[i] = c; cand[ixj] = a; }
            }
            __syncthreads();
        }
    }

    // ---- emit top-300 ----
    const float o0 = osizes[2 * b], o1 = osizes[2 * b + 1];
    for (int r = tid; r < NTOP; r += THREADS) {
        unsigned long long c = cand[r];
        float sc = __uint_as_float((unsigned)(c >> 32));
        unsigned idx = ~((unsigned)c);
        unsigned q = idx / NCLS;
        unsigned cls = idx - q * NCLS;
        out_scores[(size_t)b * NTOP + r] = sc;
        out_labels[(size_t)b * NTOP + r] = (float)cls;
        float4 pb = ((const float4*)pboxes)[(size_t)b * NTOP + q];
        float4 ob;
        ob.x = (pb.x - 0.5f * pb.z) * o0;
        ob.y = (pb.y - 0.5f * pb.w) * o1;
        ob.z = (pb.x + 0.5f * pb.z) * o0;
        ob.w = (pb.y + 0.5f * pb.w) * o1;
        ((float4*)out_boxes)[(size_t)b * NTOP + r] = ob;
    }
}

extern "C" void kernel_launch(void* const* d_in, const int* in_sizes, int n_in,
                              void* d_out, int out_size, void* d_ws, size_t ws_size,
                              hipStream_t stream) {
    const float* logits = (const float*)d_in[0];
    const float* pboxes = (const float*)d_in[1];
    const float* osizes = (const float*)d_in[2];
    const int B = in_sizes[2] / 2;

    float* out_boxes  = (float*)d_out;                       // B*300*4
    float* out_labels = out_boxes + (size_t)B * NTOP * 4;    // B*300
    float* out_scores = out_labels + (size_t)B * NTOP;       // B*300

    hipLaunchKernelGGL(postproc_kernel, dim3(B), dim3(THREADS), 0, stream,
                       logits, pboxes, osizes, out_boxes, out_labels, out_scores);
}

// Round 2
// 115.012 us; speedup vs baseline: 1.3092x; 1.3092x over previous
//
#include <hip/hip_runtime.h>
#include <cmath>

#define THREADS 256
#define QC 24000
#define NCLS 80
#define NTOP 300
#define NHIST 4096
#define CAND_CAP 1024

// monotonic unsigned key for fp32 (total order matching float compare)
__device__ __forceinline__ unsigned fkey(float x) {
    unsigned b = __float_as_uint(x);
    return (b & 0x80000000u) ? ~b : (b | 0x80000000u);
}

// inverse of fkey
__device__ __forceinline__ float fkey_inv(unsigned key) {
    unsigned b = (key & 0x80000000u) ? (key & 0x7fffffffu) : ~key;
    return __uint_as_float(b);
}

// Replicate float32 sigmoid: 1/(1+expf(-x)) with correctly-rounded expf.
__device__ __forceinline__ float sigmoid_ref(float x) {
    float ef = (float)exp(-(double)x);
    return 1.0f / (1.0f + ef);
}

__global__ __launch_bounds__(THREADS, 6) void postproc_kernel(
    const float* __restrict__ logits,   // [B, 300, 80]
    const float* __restrict__ pboxes,   // [B, 300, 4]
    const float* __restrict__ osizes,   // [B, 2]
    float* __restrict__ out_boxes,      // [B, 300, 4]
    float* __restrict__ out_labels,     // [B, 300] (as float)
    float* __restrict__ out_scores)     // [B, 300]
{
    const int b = blockIdx.x;
    const int tid = threadIdx.x;
    const float* __restrict__ row = logits + (size_t)b * QC;
    const float4* __restrict__ row4 = (const float4*)row;

    __shared__ unsigned hist[NHIST];
    __shared__ unsigned long long cand[CAND_CAP];
    __shared__ unsigned wsum[THREADS / 64];
    __shared__ int s_ncand;
    __shared__ unsigned s_thresh;

    for (int i = tid; i < NHIST; i += THREADS) hist[i] = 0u;
    if (tid == 0) s_ncand = 0;
    __syncthreads();

    // ---- pass 1: histogram of top-12 key bits ----
    for (int i = tid; i < QC / 4; i += THREADS) {
        float4 v = row4[i];
        atomicAdd(&hist[fkey(v.x) >> 20], 1u);
        atomicAdd(&hist[fkey(v.y) >> 20], 1u);
        atomicAdd(&hist[fkey(v.z) >> 20], 1u);
        atomicAdd(&hist[fkey(v.w) >> 20], 1u);
    }
    __syncthreads();

    // ---- suffix scan (descending buckets), shfl-based ----
    const int CHUNK = NHIST / THREADS;               // 16
    const int base = NHIST - 1 - tid * CHUNK;        // my chunk: base .. base-15
    unsigned partial = 0;
    #pragma unroll
    for (int s = 0; s < CHUNK; ++s) partial += hist[base - s];

    unsigned run = partial;
    #pragma unroll
    for (int d = 1; d < 64; d <<= 1) {
        unsigned v = __shfl_up(run, d, 64);
        if ((tid & 63) >= d) run += v;
    }
    if ((tid & 63) == 63) wsum[tid >> 6] = run;
    __syncthreads();
    unsigned off = 0;
    for (int w = 0; w < (tid >> 6); ++w) off += wsum[w];
    unsigned incl = run + off;
    unsigned excl = incl - partial;

    if (excl < NTOP && incl >= NTOP) {      // crossing inside my chunk (unique thread)
        unsigned cum = excl;
        #pragma unroll
        for (int s = 0; s < CHUNK; ++s) {
            cum += hist[base - s];
            if (cum >= NTOP) { s_thresh = (unsigned)(base - s) << 20; break; }
        }
    }
    __syncthreads();
    const unsigned thresh = s_thresh;

    // ---- pass 2: collect candidates (key_bits << 32 | ~idx), no sigmoid ----
    for (int i = tid; i < QC / 4; i += THREADS) {
        float4 v = row4[i];
        float vals[4] = {v.x, v.y, v.z, v.w};
        #pragma unroll
        for (int s = 0; s < 4; ++s) {
            unsigned k = fkey(vals[s]);
            if (k >= thresh) {
                int pos = atomicAdd(&s_ncand, 1);
                if (pos < CAND_CAP) {
                    unsigned idx = (unsigned)(i * 4 + s);
                    cand[pos] = ((unsigned long long)k << 32)
                              | (unsigned long long)(~idx);
                }
            }
        }
    }
    __syncthreads();
    const int ncand = min(s_ncand, CAND_CAP);

    // ---- dense sigmoid over candidates: replace key with score bits ----
    for (int i = tid; i < ncand; i += THREADS) {
        unsigned long long c = cand[i];
        float x = fkey_inv((unsigned)(c >> 32));
        float sc = sigmoid_ref(x);
        cand[i] = ((unsigned long long)__float_as_uint(sc) << 32)
                | (c & 0xffffffffull);
    }

    int npad = 512;
    while (npad < ncand) npad <<= 1;
    for (int i = ncand + tid; i < npad; i += THREADS) cand[i] = 0ull;
    __syncthreads();

    // ---- bitonic sort, descending on composite (score, ~idx) ----
    for (int k = 2; k <= npad; k <<= 1) {
        for (int j = k >> 1; j > 0; j >>= 1) {
            for (int t = tid; t < (npad >> 1); t += THREADS) {
                int i = ((t & ~(j - 1)) << 1) | (t & (j - 1));
                int ixj = i | j;
                unsigned long long a = cand[i], c = cand[ixj];
                bool desc = (i & k) == 0;
                bool sw = desc ? (a < c) : (a > c);
                if (sw) { cand[i] = c; cand[ixj] = a; }
            }
            __syncthreads();
        }
    }

    // ---- emit top-300 ----
    const float o0 = osizes[2 * b], o1 = osizes[2 * b + 1];
    for (int r = tid; r < NTOP; r += THREADS) {
        unsigned long long c = cand[r];
        float sc = __uint_as_float((unsigned)(c >> 32));
        unsigned idx = ~((unsigned)c);
        unsigned q = idx / NCLS;
        unsigned cls = idx - q * NCLS;
        out_scores[(size_t)b * NTOP + r] = sc;
        out_labels[(size_t)b * NTOP + r] = (float)cls;
        float4 pb = ((const float4*)pboxes)[(size_t)b * NTOP + q];
        float4 ob;
        ob.x = (pb.x - 0.5f * pb.z) * o0;
        ob.y = (pb.y - 0.5f * pb.w) * o1;
        ob.z = (pb.x + 0.5f * pb.z) * o0;
        ob.w = (pb.y + 0.5f * pb.w) * o1;
        ((float4*)out_boxes)[(size_t)b * NTOP + r] = ob;
    }
}

extern "C" void kernel_launch(void* const* d_in, const int* in_sizes, int n_in,
                              void* d_out, int out_size, void* d_ws, size_t ws_size,
                              hipStream_t stream) {
    const float* logits = (const float*)d_in[0];
    const float* pboxes = (const float*)d_in[1];
    const float* osizes = (const float*)d_in[2];
    const int B = in_sizes[2] / 2;

    float* out_boxes  = (float*)d_out;                       // B*300*4
    float* out_labels = out_boxes + (size_t)B * NTOP * 4;    // B*300
    float* out_scores = out_labels + (size_t)B * NTOP;       // B*300

    hipLaunchKernelGGL(postproc_kernel, dim3(B), dim3(THREADS), 0, stream,
                       logits, pboxes, osizes, out_boxes, out_labels, out_scores);
}

// Round 3
// 58.715 us; speedup vs baseline: 2.5646x; 1.9588x over previous
//
#include <hip/hip_runtime.h>
#include <cmath>

#define THREADS 256
#define QC 24000
#define NQ4 (QC / 4)
#define NCLS 80
#define NTOP 300
#define NHIST 4096
#define CAND_CAP 1024

typedef unsigned long long ull;

// monotonic unsigned key for fp32 (total order matching float compare)
__device__ __forceinline__ unsigned fkey(float x) {
    unsigned b = __float_as_uint(x);
    return (b & 0x80000000u) ? ~b : (b | 0x80000000u);
}
__device__ __forceinline__ float fkey_inv(unsigned key) {
    unsigned b = (key & 0x80000000u) ? (key & 0x7fffffffu) : ~key;
    return __uint_as_float(b);
}
// Replicate float32 sigmoid: 1/(1+expf(-x)); double exp rounds to CR expf.
__device__ __forceinline__ float sigmoid_ref(float x) {
    float ef = (float)exp(-(double)x);
    return 1.0f / (1.0f + ef);
}

__global__ __launch_bounds__(THREADS, 8) void postproc_kernel(
    const float* __restrict__ logits,   // [B, 300, 80]
    const float* __restrict__ pboxes,   // [B, 300, 4]
    const float* __restrict__ osizes,   // [B, 2]
    float* __restrict__ out_boxes,      // [B, 300, 4]
    float* __restrict__ out_labels,     // [B, 300]
    float* __restrict__ out_scores)     // [B, 300]
{
    const int b = blockIdx.x;
    const int tid = threadIdx.x;
    const int lane = tid & 63;
    const float* __restrict__ row = logits + (size_t)b * QC;
    const float4* __restrict__ row4 = (const float4*)row;

    __shared__ ull cand[CAND_CAP];          // 8 KB
    __shared__ unsigned hist[NHIST / 2];    // 8 KB, packed 2x u16 (fallback only)
    __shared__ unsigned wsum[THREADS / 64];
    __shared__ int s_ncand;
    __shared__ unsigned s_thresh;

    if (tid == 0) s_ncand = 0;
    __syncthreads();

    // Speculative static threshold: rank-300 logit for this distribution is
    // ~2.24; 2.11 keeps ~420 +- 20 candidates/row. Checked below; full
    // histogram fallback if the speculation is invalid for any row.
    const unsigned K0 = fkey(2.11f);

    // wave-aggregated candidate push (1 LDS atomic per wave-slot)
    auto push = [&](unsigned k, unsigned idx) {
        bool pred = k >= K0;
        ull mask = __ballot(pred);
        if (mask) {
            int leader = __ffsll((long long)mask) - 1;
            int base = 0;
            if (lane == leader) base = atomicAdd(&s_ncand, __popcll(mask));
            base = __shfl(base, leader, 64);
            if (pred) {
                int pos = base + __popcll(mask & ((1ull << lane) - 1));
                if (pos < CAND_CAP)
                    cand[pos] = ((ull)k << 32) | (ull)(~idx);
            }
        }
    };

    // ---- single pass: 4x unrolled loads for ILP ----
    int i = tid;
    for (; i < NQ4 - 768; i += 1024) {
        float4 a = row4[i];
        float4 c = row4[i + 256];
        float4 d = row4[i + 512];
        float4 e = row4[i + 768];
        push(fkey(a.x), 4 * i + 0);       push(fkey(a.y), 4 * i + 1);
        push(fkey(a.z), 4 * i + 2);       push(fkey(a.w), 4 * i + 3);
        push(fkey(c.x), 4 * (i + 256));   push(fkey(c.y), 4 * (i + 256) + 1);
        push(fkey(c.z), 4 * (i + 256) + 2); push(fkey(c.w), 4 * (i + 256) + 3);
        push(fkey(d.x), 4 * (i + 512));   push(fkey(d.y), 4 * (i + 512) + 1);
        push(fkey(d.z), 4 * (i + 512) + 2); push(fkey(d.w), 4 * (i + 512) + 3);
        push(fkey(e.x), 4 * (i + 768));   push(fkey(e.y), 4 * (i + 768) + 1);
        push(fkey(e.z), 4 * (i + 768) + 2); push(fkey(e.w), 4 * (i + 768) + 3);
    }
    for (; i < NQ4; i += 256) {
        float4 a = row4[i];
        push(fkey(a.x), 4 * i + 0);
        push(fkey(a.y), 4 * i + 1);
        push(fkey(a.z), 4 * i + 2);
        push(fkey(a.w), 4 * i + 3);
    }
    __syncthreads();
    int nc = s_ncand;

    // ---- fallback: exact histogram path (block-uniform branch) ----
    if (nc < NTOP || nc > CAND_CAP) {
        for (int j = tid; j < NHIST / 2; j += THREADS) hist[j] = 0u;
        __syncthreads();
        for (int j = tid; j < NQ4; j += THREADS) {
            float4 v = row4[j];
            float vals[4] = {v.x, v.y, v.z, v.w};
            #pragma unroll
            for (int s = 0; s < 4; ++s) {
                unsigned bin = fkey(vals[s]) >> 20;
                atomicAdd(&hist[bin >> 1], (bin & 1) ? 0x10000u : 1u);
            }
        }
        __syncthreads();
        const int CHUNK = NHIST / THREADS;          // 16
        const int base = NHIST - 1 - tid * CHUNK;
        unsigned partial = 0;
        #pragma unroll
        for (int s = 0; s < CHUNK; ++s) {
            int bin = base - s;
            partial += (hist[bin >> 1] >> ((bin & 1) * 16)) & 0xffffu;
        }
        unsigned run = partial;
        #pragma unroll
        for (int d = 1; d < 64; d <<= 1) {
            unsigned v = __shfl_up(run, d, 64);
            if (lane >= d) run += v;
        }
        if (lane == 63) wsum[tid >> 6] = run;
        __syncthreads();
        unsigned off = 0;
        for (int w = 0; w < (tid >> 6); ++w) off += wsum[w];
        unsigned incl = run + off, excl = incl - partial;
        if (excl < NTOP && incl >= NTOP) {
            unsigned cum = excl;
            #pragma unroll
            for (int s = 0; s < CHUNK; ++s) {
                int bin = base - s;
                cum += (hist[bin >> 1] >> ((bin & 1) * 16)) & 0xffffu;
                if (cum >= NTOP) { s_thresh = (unsigned)bin << 20; break; }
            }
        }
        if (tid == 0) s_ncand = 0;
        __syncthreads();
        const unsigned T = s_thresh;
        for (int j = tid; j < NQ4; j += THREADS) {
            float4 v = row4[j];
            float vals[4] = {v.x, v.y, v.z, v.w};
            #pragma unroll
            for (int s = 0; s < 4; ++s) {
                unsigned k = fkey(vals[s]);
                if (k >= T) {
                    int pos = atomicAdd(&s_ncand, 1);
                    if (pos < CAND_CAP)
                        cand[pos] = ((ull)k << 32) | (ull)(~(unsigned)(4 * j + s));
                }
            }
        }
        __syncthreads();
        nc = min(s_ncand, CAND_CAP);
    }

    // ---- dense sigmoid over candidates: replace logit key with score bits
    //      (sort MUST be on sigmoid bits to reproduce ref tie ordering) ----
    for (int j = tid; j < nc; j += THREADS) {
        ull c = cand[j];
        float x = fkey_inv((unsigned)(c >> 32));
        float sc = sigmoid_ref(x);
        cand[j] = ((ull)__float_as_uint(sc) << 32) | (c & 0xffffffffull);
    }

    int npad = 512;
    while (npad < nc) npad <<= 1;
    for (int j = nc + tid; j < npad; j += THREADS) cand[j] = 0ull;
    __syncthreads();

    // ---- bitonic sort, descending on composite (score, ~idx) ----
    for (int k = 2; k <= npad; k <<= 1) {
        for (int j = k >> 1; j > 0; j >>= 1) {
            for (int t = tid; t < (npad >> 1); t += THREADS) {
                int u = ((t & ~(j - 1)) << 1) | (t & (j - 1));
                int uxj = u | j;
                ull a = cand[u], c = cand[uxj];
                bool desc = (u & k) == 0;
                bool sw = desc ? (a < c) : (a > c);
                if (sw) { cand[u] = c; cand[uxj] = a; }
            }
            __syncthreads();
        }
    }

    // ---- emit top-300 ----
    const float o0 = osizes[2 * b], o1 = osizes[2 * b + 1];
    for (int r = tid; r < NTOP; r += THREADS) {
        ull c = cand[r];
        float sc = __uint_as_float((unsigned)(c >> 32));
        unsigned idx = ~((unsigned)c);
        unsigned q = idx / NCLS;
        unsigned cls = idx - q * NCLS;
        out_scores[(size_t)b * NTOP + r] = sc;
        out_labels[(size_t)b * NTOP + r] = (float)cls;
        float4 pb = ((const float4*)pboxes)[(size_t)b * NTOP + q];
        float4 ob;
        ob.x = (pb.x - 0.5f * pb.z) * o0;
        ob.y = (pb.y - 0.5f * pb.w) * o1;
        ob.z = (pb.x + 0.5f * pb.z) * o0;
        ob.w = (pb.y + 0.5f * pb.w) * o1;
        ((float4*)out_boxes)[(size_t)b * NTOP + r] = ob;
    }
}

extern "C" void kernel_launch(void* const* d_in, const int* in_sizes, int n_in,
                              void* d_out, int out_size, void* d_ws, size_t ws_size,
                              hipStream_t stream) {
    const float* logits = (const float*)d_in[0];
    const float* pboxes = (const float*)d_in[1];
    const float* osizes = (const float*)d_in[2];
    const int B = in_sizes[2] / 2;

    float* out_boxes  = (float*)d_out;                       // B*300*4
    float* out_labels = out_boxes + (size_t)B * NTOP * 4;    // B*300
    float* out_scores = out_labels + (size_t)B * NTOP;       // B*300

    hipLaunchKernelGGL(postproc_kernel, dim3(B), dim3(THREADS), 0, stream,
                       logits, pboxes, osizes, out_boxes, out_labels, out_scores);
}